// Round 15
// baseline (472.014 us; speedup 1.0000x reference)
//
#include <hip/hip_runtime.h>

#define M_NODES 100000
#define PADM 100032   // 1563 * 64
#define DIM 128
#define N_EDGES_TOT 1600000
#define NBKT 256
#define NPB 391
#define BKT_CAP 8192
#define ECHUNK 4096
#define INVN 1e-5f    // 1/100000
#define NREP 8        // stat-slot replicas (8 XCDs)

typedef unsigned int uint;
typedef unsigned short ushort;
typedef __attribute__((ext_vector_type(8))) short bf16x8;
typedef __attribute__((ext_vector_type(4))) float f32x4;

__device__ __forceinline__ float bflo(uint u) { return __uint_as_float(u << 16); }
__device__ __forceinline__ float bfhi(uint u) { return __uint_as_float(u & 0xffff0000u); }
__device__ __forceinline__ float bf2f(ushort h) { return __uint_as_float(((uint)h) << 16); }
__device__ __forceinline__ ushort f2bf(float f) {
    uint u = __float_as_uint(f);
    return (ushort)((u + 0x7fffu + ((u >> 16) & 1u)) >> 16);
}

// ---------------------------------------------------------------------------
__global__ void k_cvt(const float* __restrict__ x, ushort* __restrict__ xb,
                      int n4) {
    int i = blockIdx.x * 256 + threadIdx.x;
    if (i >= n4) return;
    float4 v = ((const float4*)x)[i];
    uint2 r;
    r.x = (uint)f2bf(v.x) | ((uint)f2bf(v.y) << 16);
    r.y = (uint)f2bf(v.z) | ((uint)f2bf(v.w) << 16);
    ((uint2*)xb)[i] = r;
}

// W prep + stat-slot zeroing fused.
__global__ void k_wprep(const float* __restrict__ W1,
                        const float* __restrict__ W2, ushort* __restrict__ Wh,
                        ushort* __restrict__ Wl, float* __restrict__ st,
                        int nSt) {
    int i = blockIdx.x * 256 + threadIdx.x;
    if (i < nSt) st[i] = 0.f;
    if (i >= 6 * 16384) return;
    int l = i >> 14;
    int r = i & 16383;
    int n = r >> 7, k = r & 127;
    const float* W = (l < 3) ? (W1 + l * 16384) : (W2 + (l - 3) * 16384);
    float w = W[k * 128 + n];
    ushort h = f2bf(w);
    Wh[i] = h;
    Wl[i] = f2bf(w - bf2f(h));
}

// ---------------------------------------------------------------------------
// CSR build, bucket-radix, no global atomics.  4096-edge chunks; pairs
// packed into 32 bits: (dstLocal<<17)|src.
__global__ void k_bhist(const int* __restrict__ dst, int* __restrict__ cntM,
                        int nE, int nChunks) {
    __shared__ int h[NBKT];
    const int chunk = blockIdx.x, t = threadIdx.x;
    h[t] = 0;
    __syncthreads();
    const int e0 = chunk * ECHUNK;
#pragma unroll
    for (int k = 0; k < 16; ++k) {
        int e = e0 + k * 256 + t;
        if (e < nE) atomicAdd(&h[dst[e] / NPB], 1);
    }
    __syncthreads();
    cntM[t * nChunks + chunk] = h[t];
}

__global__ void k_scanA(int* __restrict__ cnt, int* __restrict__ bsum, int n) {
    __shared__ int s[256];
    int t = threadIdx.x, i = blockIdx.x * 256 + t;
    int v = (i < n) ? cnt[i] : 0;
    s[t] = v;
    __syncthreads();
#pragma unroll
    for (int o = 1; o < 256; o <<= 1) {
        int a = (t >= o) ? s[t - o] : 0;
        __syncthreads();
        s[t] += a;
        __syncthreads();
    }
    if (i < n) cnt[i] = s[t] - v;
    if (t == 255) bsum[blockIdx.x] = s[255];
}

__global__ void k_scanB(int* bsum, int nB) {
    __shared__ int s[1024];
    int t = threadIdx.x;
    int v = (t < nB) ? bsum[t] : 0;
    s[t] = v;
    __syncthreads();
#pragma unroll
    for (int o = 1; o < 1024; o <<= 1) {
        int a = (t >= o) ? s[t - o] : 0;
        __syncthreads();
        s[t] += a;
        __syncthreads();
    }
    if (t < nB) bsum[t] = s[t] - v;
}

__global__ void k_scanC(int* __restrict__ excl, const int* __restrict__ bsum) {
    int i = blockIdx.x * 256 + threadIdx.x;
    excl[i] += bsum[blockIdx.x];
}

__global__ void k_pairs(const int* __restrict__ src, const int* __restrict__ dst,
                        const int* __restrict__ exclM, uint* __restrict__ pairs,
                        int nE, int nChunks) {
    __shared__ int base[NBKT];
    const int chunk = blockIdx.x, t = threadIdx.x;
    base[t] = exclM[t * nChunks + chunk];
    __syncthreads();
    const int e0 = chunk * ECHUNK;
#pragma unroll
    for (int k = 0; k < 16; ++k) {
        int e = e0 + k * 256 + t;
        if (e < nE) {
            int d = dst[e];
            int bkt = d / NPB;
            int pos = atomicAdd(&base[bkt], 1);
            pairs[pos] = ((uint)(d - bkt * NPB) << 17) | (uint)src[e];
        }
    }
}

__global__ void k_csrD(const uint* __restrict__ pairs,
                       const int* __restrict__ exclM, int nChunks,
                       int* __restrict__ rowptr, int* __restrict__ srcs,
                       int nE) {
    __shared__ int cnt[512];
    __shared__ int scn[512];
    __shared__ int sl[BKT_CAP];
    const int b = blockIdx.x, t = threadIdx.x;
    const int base = exclM[b * nChunks];
    const int next = (b == NBKT - 1) ? nE : exclM[(b + 1) * nChunks];
    const int count = next - base;
    const int nodeBase = b * NPB;
    const int nNodes = min(NPB, M_NODES - nodeBase);
    cnt[t] = 0;
    cnt[t + 256] = 0;
    __syncthreads();
    for (int i = t; i < count; i += 256)
        atomicAdd(&cnt[pairs[base + i] >> 17], 1);
    __syncthreads();
    scn[t] = cnt[t];
    scn[t + 256] = cnt[t + 256];
    __syncthreads();
#pragma unroll
    for (int o = 1; o < 512; o <<= 1) {
        int a0 = (t >= o) ? scn[t - o] : 0;
        int a1 = scn[t + 256 - o];
        __syncthreads();
        scn[t] += a0;
        scn[t + 256] += a1;
        __syncthreads();
    }
    int o0 = scn[t] - cnt[t];
    int o1 = scn[t + 256] - cnt[t + 256];
    __syncthreads();
    cnt[t] = o0;
    cnt[t + 256] = o1;
    if (t < nNodes) rowptr[nodeBase + t] = base + o0;
    if (t + 256 < nNodes) rowptr[nodeBase + t + 256] = base + o1;
    if (b == 0 && t == 0) rowptr[M_NODES] = nE;
    __syncthreads();
    const bool inLds = (count <= BKT_CAP);
    for (int i = t; i < count; i += 256) {
        uint p = pairs[base + i];
        int pos = atomicAdd(&cnt[p >> 17], 1);
        int sv = (int)(p & 0x1FFFFu);
        if (inLds) sl[pos] = sv;
        else srcs[base + pos] = sv;
    }
    __syncthreads();
    if (inLds)
        for (int i = t; i < count; i += 256) srcs[base + i] = sl[i];
}

// ---------------------------------------------------------------------------
// Gather with fused BN+ReLU (coef table built once per block in LDS).
// 32 lanes x 4 channels, 8 row-loads in flight, f32 acc, split planes out.
__global__ void k_gather(const ushort* __restrict__ h,
                         const int* __restrict__ rowptr,
                         const int* __restrict__ srcs,
                         const float* __restrict__ bnstats,
                         const float* __restrict__ gamma,
                         const float* __restrict__ beta,
                         ushort* __restrict__ AGh, ushort* __restrict__ AGl,
                         int M) {
    __shared__ float coef[256];
    int t = threadIdx.x;
    const bool bn = (bnstats != nullptr);
    if (bn) {
        if (t < 128) {
            float s0 = 0.f, q0 = 0.f;
#pragma unroll
            for (int r = 0; r < NREP; ++r) {
                s0 += bnstats[r * 256 + t];
                q0 += bnstats[r * 256 + 128 + t];
            }
            float mu = s0 * INVN;
            float var = q0 * INVN - mu * mu;
            float s = gamma[t] * rsqrtf(var + 1e-5f);
            coef[t] = s;
            coef[128 + t] = beta[t] - mu * s;
        }
        __syncthreads();
    }
    int node = blockIdx.x * 8 + (t >> 5);
    if (node >= M) return;
    int c = (t & 31) * 4;
    float sc0 = 1.f, sc1 = 1.f, sc2 = 1.f, sc3 = 1.f;
    float sh0 = 0.f, sh1 = 0.f, sh2 = 0.f, sh3 = 0.f;
    if (bn) {
        sc0 = coef[c]; sc1 = coef[c + 1]; sc2 = coef[c + 2]; sc3 = coef[c + 3];
        sh0 = coef[128 + c]; sh1 = coef[129 + c];
        sh2 = coef[130 + c]; sh3 = coef[131 + c];
    }
    int beg = rowptr[node];
    int end = rowptr[node + 1];

    uint2 v = *(const uint2*)(h + (size_t)node * DIM + c);
    float a0, a1, a2, a3;
    if (bn) {
        a0 = fmaxf(fmaf(bflo(v.x), sc0, sh0), 0.f);
        a1 = fmaxf(fmaf(bfhi(v.x), sc1, sh1), 0.f);
        a2 = fmaxf(fmaf(bflo(v.y), sc2, sh2), 0.f);
        a3 = fmaxf(fmaf(bfhi(v.y), sc3, sh3), 0.f);
    } else {
        a0 = bflo(v.x); a1 = bfhi(v.x); a2 = bflo(v.y); a3 = bfhi(v.y);
    }
    float b0 = 0.f, b1 = 0.f, b2 = 0.f, b3 = 0.f;

    int j = beg;
    for (; j + 8 <= end; j += 8) {
        int s[8];
#pragma unroll
        for (int k = 0; k < 8; ++k) s[k] = srcs[j + k];
        uint2 g[8];
#pragma unroll
        for (int k = 0; k < 8; ++k)
            g[k] = *(const uint2*)(h + (size_t)s[k] * DIM + c);
        if (bn) {
#pragma unroll
            for (int k = 0; k < 8; k += 2) {
                a0 += fmaxf(fmaf(bflo(g[k].x), sc0, sh0), 0.f);
                a1 += fmaxf(fmaf(bfhi(g[k].x), sc1, sh1), 0.f);
                a2 += fmaxf(fmaf(bflo(g[k].y), sc2, sh2), 0.f);
                a3 += fmaxf(fmaf(bfhi(g[k].y), sc3, sh3), 0.f);
                b0 += fmaxf(fmaf(bflo(g[k + 1].x), sc0, sh0), 0.f);
                b1 += fmaxf(fmaf(bfhi(g[k + 1].x), sc1, sh1), 0.f);
                b2 += fmaxf(fmaf(bflo(g[k + 1].y), sc2, sh2), 0.f);
                b3 += fmaxf(fmaf(bfhi(g[k + 1].y), sc3, sh3), 0.f);
            }
        } else {
#pragma unroll
            for (int k = 0; k < 8; k += 2) {
                a0 += bflo(g[k].x); a1 += bfhi(g[k].x);
                a2 += bflo(g[k].y); a3 += bfhi(g[k].y);
                b0 += bflo(g[k + 1].x); b1 += bfhi(g[k + 1].x);
                b2 += bflo(g[k + 1].y); b3 += bfhi(g[k + 1].y);
            }
        }
    }
    for (; j < end; ++j) {
        int s = srcs[j];
        uint2 g = *(const uint2*)(h + (size_t)s * DIM + c);
        if (bn) {
            a0 += fmaxf(fmaf(bflo(g.x), sc0, sh0), 0.f);
            a1 += fmaxf(fmaf(bfhi(g.x), sc1, sh1), 0.f);
            a2 += fmaxf(fmaf(bflo(g.y), sc2, sh2), 0.f);
            a3 += fmaxf(fmaf(bfhi(g.y), sc3, sh3), 0.f);
        } else {
            a0 += bflo(g.x); a1 += bfhi(g.x); a2 += bflo(g.y); a3 += bfhi(g.y);
        }
    }
    float s0 = a0 + b0, s1 = a1 + b1, s2 = a2 + b2, s3 = a3 + b3;
    ushort h0 = f2bf(s0), h1 = f2bf(s1), h2 = f2bf(s2), h3 = f2bf(s3);
    ushort l0 = f2bf(s0 - bf2f(h0)), l1 = f2bf(s1 - bf2f(h1));
    ushort l2 = f2bf(s2 - bf2f(h2)), l3 = f2bf(s3 - bf2f(h3));
    uint2 hp, lp;
    hp.x = (uint)h0 | ((uint)h1 << 16);
    hp.y = (uint)h2 | ((uint)h3 << 16);
    lp.x = (uint)l0 | ((uint)l1 << 16);
    lp.y = (uint)l2 | ((uint)l3 << 16);
    size_t ix = (size_t)node * DIM + c;
    *(uint2*)(AGh + ix) = hp;
    *(uint2*)(AGl + ix) = lp;
}

// ---------------------------------------------------------------------------
// GEMM A: C = (Ah+Al) @ W + bias.  Staging now via async global_load_lds
// (width 16): LDS dest is LINEAR (wave-uniform base + lane*16); the swizzle
// is applied by permuting the GLOBAL source column (cb ^ (r&15)), yielding
// the identical swizzled layout with no VGPR round-trip.
__global__ void __launch_bounds__(256, 4) k_gemmA(
    ushort* __restrict__ Ah, const ushort* __restrict__ Al,
    const ushort* __restrict__ Wh, const ushort* __restrict__ Wl,
    const float* __restrict__ bias, float* __restrict__ statSlot, int M) {
    __shared__ ushort lds[16384];  // 32 KB
    const int t = threadIdx.x;
    const int w = t >> 6, lane = t & 63, rq = lane >> 4, rc = lane & 15;
    const int row0 = blockIdx.x * 64;

    bf16x8 wh[4][2], wl[4][2];
#pragma unroll
    for (int kc = 0; kc < 4; ++kc)
#pragma unroll
        for (int jj = 0; jj < 2; ++jj) {
            size_t off = (size_t)(w * 32 + jj * 16 + rc) * DIM + kc * 32 + rq * 8;
            wh[kc][jj] = *(const bf16x8*)(Wh + off);
            wl[kc][jj] = *(const bf16x8*)(Wl + off);
        }

#pragma unroll
    for (int i = 0; i < 8; ++i) {
        int idx = t + i * 256;
        int pl = idx >> 10;
        int r = (idx >> 4) & 63;
        int cb = idx & 15;
        int cbs = cb ^ (r & 15);  // pre-swizzled source column
        const ushort* p = pl ? Al : Ah;
        const ushort* g = p + (size_t)(row0 + r) * DIM + cbs * 8;
        __builtin_amdgcn_global_load_lds(
            (const __attribute__((address_space(1))) void*)g,
            (__attribute__((address_space(3))) void*)((char*)lds + idx * 16),
            16, 0, 0);
    }
    __syncthreads();

    f32x4 acc[4][2];
#pragma unroll
    for (int i = 0; i < 4; ++i)
#pragma unroll
        for (int jj = 0; jj < 2; ++jj) acc[i][jj] = (f32x4){0.f, 0.f, 0.f, 0.f};

#pragma unroll
    for (int kc = 0; kc < 4; ++kc) {
        const int kb = kc * 64 + rq * 16;
#pragma unroll
        for (int i = 0; i < 4; ++i) {
            int lr = i * 16 + rc;
            int so = lr * 256 + (kb ^ ((lr & 15) << 4));
            bf16x8 ah = *(const bf16x8*)((char*)lds + so);
            bf16x8 al = *(const bf16x8*)((char*)lds + 16384 + so);
#pragma unroll
            for (int jj = 0; jj < 2; ++jj) {
                acc[i][jj] = __builtin_amdgcn_mfma_f32_16x16x32_bf16(ah, wh[kc][jj], acc[i][jj], 0, 0, 0);
                acc[i][jj] = __builtin_amdgcn_mfma_f32_16x16x32_bf16(al, wh[kc][jj], acc[i][jj], 0, 0, 0);
                acc[i][jj] = __builtin_amdgcn_mfma_f32_16x16x32_bf16(ah, wl[kc][jj], acc[i][jj], 0, 0, 0);
            }
        }
    }

    float bc[2] = {bias[w * 32 + rc], bias[w * 32 + 16 + rc]};
    float csum[2] = {0.f, 0.f}, csq[2] = {0.f, 0.f};

    __syncthreads();
#pragma unroll
    for (int i = 0; i < 4; ++i)
#pragma unroll
        for (int r = 0; r < 4; ++r) {
            int lrow = i * 16 + rq * 4 + r;
            bool live = (row0 + lrow) < M;
#pragma unroll
            for (int jj = 0; jj < 2; ++jj) {
                float o = acc[i][jj][r] + bc[jj];
                int off = lrow * 256 +
                          (((w * 32 + jj * 16 + rc) * 2) ^ ((lrow & 15) << 4));
                *(ushort*)((char*)lds + off) = f2bf(o);
                if (live) { csum[jj] += o; csq[jj] += o * o; }
            }
        }
    __syncthreads();
    {
        int lrow = w * 16 + (lane & 15);
        int kq = lane >> 4;
        ushort* dH = Ah + (size_t)row0 * DIM;
#pragma unroll
        for (int kc = 0; kc < 4; ++kc) {
            int off = lrow * 256 + ((kc * 64 + kq * 16) ^ ((lrow & 15) << 4));
            uint4 H = *(uint4*)((char*)lds + off);
            size_t go = ((size_t)(w * 4 + kc) * 64 + lane) * 8;
            *(uint4*)(dH + go) = H;
        }
    }
#pragma unroll
    for (int jj = 0; jj < 2; ++jj) {
        csum[jj] += __shfl_xor(csum[jj], 16);
        csum[jj] += __shfl_xor(csum[jj], 32);
        csq[jj] += __shfl_xor(csq[jj], 16);
        csq[jj] += __shfl_xor(csq[jj], 32);
    }
    float* slot = statSlot + (blockIdx.x & (NREP - 1)) * 256;
    if (lane < 16) {
        atomicAdd(slot + w * 32 + rc, csum[0]);
        atomicAdd(slot + w * 32 + 16 + rc, csum[1]);
        atomicAdd(slot + 128 + w * 32 + rc, csq[0]);
        atomicAdd(slot + 128 + w * 32 + 16 + rc, csq[1]);
    }
}

// ---------------------------------------------------------------------------
// GEMM B: C = BNrelu(Ch) @ W + bias.  (unchanged)
__global__ void __launch_bounds__(256, 4) k_gemmB(
    const ushort* __restrict__ Ch,
    const ushort* __restrict__ Wh, const ushort* __restrict__ Wl,
    const float* __restrict__ bias, const float* __restrict__ bnstats,
    const float* __restrict__ gamma, const float* __restrict__ beta,
    ushort* __restrict__ Cb, float* __restrict__ outF,
    float* __restrict__ statSlot, int M) {
    __shared__ char smem[16384];
    const int t = threadIdx.x;
    const int w = t >> 6, lane = t & 63, rq = lane >> 4, rc = lane & 15;
    const int row0 = blockIdx.x * 64;

    bf16x8 wh[4][2], wl[4][2];
#pragma unroll
    for (int kc = 0; kc < 4; ++kc)
#pragma unroll
        for (int jj = 0; jj < 2; ++jj) {
            size_t off = (size_t)(w * 32 + jj * 16 + rc) * DIM + kc * 32 + rq * 8;
            wh[kc][jj] = *(const bf16x8*)(Wh + off);
            wl[kc][jj] = *(const bf16x8*)(Wl + off);
        }

    float* coef = (float*)smem;
    if (t < 128) {
        float s0 = 0.f, q0 = 0.f;
#pragma unroll
        for (int r = 0; r < NREP; ++r) {
            s0 += bnstats[r * 256 + t];
            q0 += bnstats[r * 256 + 128 + t];
        }
        float mu = s0 * INVN;
        float var = q0 * INVN - mu * mu;
        float s = gamma[t] * rsqrtf(var + 1e-5f);
        coef[t] = s;
        coef[128 + t] = beta[t] - mu * s;
    }
    __syncthreads();

    const ushort* pH = Ch + (size_t)row0 * DIM;
    const int kq8 = (lane >> 4) * 8;

    f32x4 acc[4][2];
#pragma unroll
    for (int i = 0; i < 4; ++i)
#pragma unroll
        for (int jj = 0; jj < 2; ++jj) acc[i][jj] = (f32x4){0.f, 0.f, 0.f, 0.f};

#pragma unroll
    for (int kc = 0; kc < 4; ++kc) {
        float sc8[8], sh8[8];
#pragma unroll
        for (int e = 0; e < 8; ++e) {
            sc8[e] = coef[kc * 32 + kq8 + e];
            sh8[e] = coef[128 + kc * 32 + kq8 + e];
        }
#pragma unroll
        for (int i = 0; i < 4; ++i) {
            size_t go = ((size_t)(i * 4 + kc) * 64 + lane) * 8;
            uint4 H = *(const uint4*)(pH + go);
            uint hu[4] = {H.x, H.y, H.z, H.w};
            uint oh[4], ol[4];
#pragma unroll
            for (int e = 0; e < 4; ++e) {
                float v0 = bflo(hu[e]);
                float v1 = bfhi(hu[e]);
                v0 = fmaxf(fmaf(v0, sc8[2 * e], sh8[2 * e]), 0.f);
                v1 = fmaxf(fmaf(v1, sc8[2 * e + 1], sh8[2 * e + 1]), 0.f);
                ushort h0 = f2bf(v0), h1 = f2bf(v1);
                oh[e] = (uint)h0 | ((uint)h1 << 16);
                ol[e] = (uint)f2bf(v0 - bf2f(h0)) |
                        ((uint)f2bf(v1 - bf2f(h1)) << 16);
            }
            uint4 AH = make_uint4(oh[0], oh[1], oh[2], oh[3]);
            uint4 AL = make_uint4(ol[0], ol[1], ol[2], ol[3]);
            bf16x8 ah = *(bf16x8*)&AH;
            bf16x8 al = *(bf16x8*)&AL;
#pragma unroll
            for (int jj = 0; jj < 2; ++jj) {
                acc[i][jj] = __builtin_amdgcn_mfma_f32_16x16x32_bf16(ah, wh[kc][jj], acc[i][jj], 0, 0, 0);
                acc[i][jj] = __builtin_amdgcn_mfma_f32_16x16x32_bf16(al, wh[kc][jj], acc[i][jj], 0, 0, 0);
                acc[i][jj] = __builtin_amdgcn_mfma_f32_16x16x32_bf16(ah, wl[kc][jj], acc[i][jj], 0, 0, 0);
            }
        }
    }

    float bc[2] = {bias[w * 32 + rc], bias[w * 32 + 16 + rc]};

    if (outF) {
#pragma unroll
        for (int i = 0; i < 4; ++i)
#pragma unroll
            for (int r = 0; r < 4; ++r)
#pragma unroll
                for (int jj = 0; jj < 2; ++jj) acc[i][jj][r] += bc[jj];
        __syncthreads();
        float* nr = (float*)smem;
#pragma unroll
        for (int i = 0; i < 4; ++i)
#pragma unroll
            for (int r = 0; r < 4; ++r) {
                float ss = acc[i][0][r] * acc[i][0][r] + acc[i][1][r] * acc[i][1][r];
                ss += __shfl_xor(ss, 1);
                ss += __shfl_xor(ss, 2);
                ss += __shfl_xor(ss, 4);
                ss += __shfl_xor(ss, 8);
                if (rc == 0) nr[(i * 16 + rq * 4 + r) * 4 + w] = ss;
            }
        __syncthreads();
#pragma unroll
        for (int i = 0; i < 4; ++i)
#pragma unroll
            for (int r = 0; r < 4; ++r) {
                int lrow = i * 16 + rq * 4 + r;
                float4 q = *(const float4*)(nr + lrow * 4);
                float inv = 1.f / fmaxf(sqrtf(q.x + q.y + q.z + q.w), 1e-12f);
                int row = row0 + lrow;
                if (row < M) {
                    outF[(size_t)row * DIM + w * 32 + rc] = acc[i][0][r] * inv;
                    outF[(size_t)row * DIM + w * 32 + 16 + rc] = acc[i][1][r] * inv;
                }
            }
        return;
    }

    float csum[2] = {0.f, 0.f}, csq[2] = {0.f, 0.f};
    __syncthreads();
#pragma unroll
    for (int i = 0; i < 4; ++i)
#pragma unroll
        for (int r = 0; r < 4; ++r) {
            int lrow = i * 16 + rq * 4 + r;
            bool live = (row0 + lrow) < M;
#pragma unroll
            for (int jj = 0; jj < 2; ++jj) {
                float o = acc[i][jj][r] + bc[jj];
                int off = lrow * 256 +
                          (((w * 32 + jj * 16 + rc) * 2) ^ ((lrow & 15) << 4));
                *(ushort*)(smem + off) = f2bf(o);
                if (live) { csum[jj] += o; csq[jj] += o * o; }
            }
        }
    __syncthreads();
#pragma unroll
    for (int it = 0; it < 4; ++it) {
        int idx = t + it * 256;
        int row = idx >> 4, cb = idx & 15;
        int grow = row0 + row;
        if (grow < M) {
            uint4 v = *(uint4*)(smem + row * 256 + ((cb * 16) ^ ((row & 15) << 4)));
            *(uint4*)(Cb + (size_t)grow * DIM + cb * 8) = v;
        }
    }
#pragma unroll
    for (int jj = 0; jj < 2; ++jj) {
        csum[jj] += __shfl_xor(csum[jj], 16);
        csum[jj] += __shfl_xor(csum[jj], 32);
        csq[jj] += __shfl_xor(csq[jj], 16);
        csq[jj] += __shfl_xor(csq[jj], 32);
    }
    float* slot = statSlot + (blockIdx.x & (NREP - 1)) * 256;
    if (lane < 16) {
        atomicAdd(slot + w * 32 + rc, csum[0]);
        atomicAdd(slot + w * 32 + 16 + rc, csum[1]);
        atomicAdd(slot + 128 + w * 32 + rc, csq[0]);
        atomicAdd(slot + 128 + w * 32 + 16 + rc, csq[1]);
    }
}

// ---------------------------------------------------------------------------
extern "C" void kernel_launch(void* const* d_in, const int* in_sizes, int n_in,
                              void* d_out, int out_size, void* d_ws,
                              size_t ws_size, hipStream_t stream) {
    const float* x = (const float*)d_in[0];
    const int* ei = (const int*)d_in[1];
    const float* W1 = (const float*)d_in[2];
    const float* b1 = (const float*)d_in[3];
    const float* g1 = (const float*)d_in[4];
    const float* be1 = (const float*)d_in[5];
    const float* W2 = (const float*)d_in[6];
    const float* b2 = (const float*)d_in[7];
    const float* g_out = (const float*)d_in[8];
    const float* b_out = (const float*)d_in[9];
    float* out = (float*)d_out;

    const int M = M_NODES;
    const int E = N_EDGES_TOT;
    const size_t NM = (size_t)M * DIM;
    const size_t PM = (size_t)PADM * DIM;
    const int nChunks = (E + ECHUNK - 1) / ECHUNK;   // 391
    const int nMat = NBKT * nChunks;                 // 100096
    const int SLOT = 256 * NREP;

    ushort* AGh = (ushort*)d_ws;
    ushort* AGl = AGh + PM;
    ushort* B0 = AGl + PM;
    ushort* Wh = B0 + NM;
    ushort* Wl = Wh + 6 * 16384;
    float* st = (float*)(Wl + 6 * 16384);
    float* stA0 = st;
    float* stA1 = st + SLOT;
    float* stA2 = st + 2 * SLOT;
    float* stB0 = st + 3 * SLOT;
    float* stB1 = st + 4 * SLOT;
    uint* pairs = (uint*)(st + 5 * SLOT);
    int* rowptr = (int*)(pairs + E);
    int* cntM = rowptr + (M + 2);
    int* bsum = cntM + nMat;
    int* srcs = bsum + 1024;

    const int* src = ei;
    const int* dst = ei + E;

    const int gemmGrid = PADM / 64;    // 1563
    const int gathGrid = (M + 7) / 8;

    // ---------------- CSR build ----------------
    k_bhist<<<nChunks, 256, 0, stream>>>(dst, cntM, E, nChunks);
    k_scanA<<<(nMat + 255) / 256, 256, 0, stream>>>(cntM, bsum, nMat);
    k_scanB<<<1, 1024, 0, stream>>>(bsum, (nMat + 255) / 256);
    k_scanC<<<(nMat + 255) / 256, 256, 0, stream>>>(cntM, bsum);
    k_pairs<<<nChunks, 256, 0, stream>>>(src, dst, cntM, pairs, E, nChunks);
    k_csrD<<<NBKT, 256, 0, stream>>>(pairs, cntM, nChunks, rowptr, srcs, E);

    // ---------------- prep ----------------
    k_cvt<<<(int)((NM / 4 + 255) / 256), 256, 0, stream>>>(x, B0, (int)(NM / 4));
    k_wprep<<<(6 * 16384 + 255) / 256, 256, 0, stream>>>(W1, W2, Wh, Wl, st, 5 * SLOT);

    // ---------------- layer 0 ----------------
    k_gather<<<gathGrid, 256, 0, stream>>>(B0, rowptr, srcs, nullptr, nullptr,
                                           nullptr, AGh, AGl, M);
    k_gemmA<<<gemmGrid, 256, 0, stream>>>(AGh, AGl, Wh, Wl, b1, stA0, M);
    k_gemmB<<<gemmGrid, 256, 0, stream>>>(AGh, Wh + 3 * 16384, Wl + 3 * 16384,
                                          b2, stA0, g1, be1, B0, nullptr, stB0, M);

    // ---------------- layer 1 (BN fused into gather) ----------------
    k_gather<<<gathGrid, 256, 0, stream>>>(B0, rowptr, srcs, stB0, g_out, b_out,
                                           AGh, AGl, M);
    k_gemmA<<<gemmGrid, 256, 0, stream>>>(AGh, AGl, Wh + 16384, Wl + 16384,
                                          b1 + 128, stA1, M);
    k_gemmB<<<gemmGrid, 256, 0, stream>>>(AGh, Wh + 4 * 16384, Wl + 4 * 16384,
                                          b2 + 128, stA1, g1 + 128, be1 + 128,
                                          B0, nullptr, stB1, M);

    // ---------------- layer 2 ----------------
    k_gather<<<gathGrid, 256, 0, stream>>>(B0, rowptr, srcs, stB1, g_out + 128,
                                           b_out + 128, AGh, AGl, M);
    k_gemmA<<<gemmGrid, 256, 0, stream>>>(AGh, AGl, Wh + 2 * 16384, Wl + 2 * 16384,
                                          b1 + 256, stA2, M);
    k_gemmB<<<gemmGrid, 256, 0, stream>>>(AGh, Wh + 5 * 16384, Wl + 5 * 16384,
                                          b2 + 256, stA2, g1 + 256, be1 + 256,
                                          nullptr, out, nullptr, M);
}

// Round 16
// 455.704 us; speedup vs baseline: 1.0358x; 1.0358x over previous
//
#include <hip/hip_runtime.h>

#define M_NODES 100000
#define PADM 100032   // 1563 * 64
#define DIM 128
#define N_EDGES_TOT 1600000
#define NBKT 256
#define NPB 391
#define BKT_CAP 8192
#define ECHUNK 4096
#define INVN 1e-5f    // 1/100000
#define NREP 8        // stat-slot replicas (8 XCDs)

typedef unsigned int uint;
typedef unsigned short ushort;
typedef __attribute__((ext_vector_type(8))) short bf16x8;
typedef __attribute__((ext_vector_type(4))) float f32x4;

__device__ __forceinline__ float bflo(uint u) { return __uint_as_float(u << 16); }
__device__ __forceinline__ float bfhi(uint u) { return __uint_as_float(u & 0xffff0000u); }
__device__ __forceinline__ float bf2f(ushort h) { return __uint_as_float(((uint)h) << 16); }
__device__ __forceinline__ ushort f2bf(float f) {
    uint u = __float_as_uint(f);
    return (ushort)((u + 0x7fffu + ((u >> 16) & 1u)) >> 16);
}

// ---------------------------------------------------------------------------
__global__ void k_cvt(const float* __restrict__ x, ushort* __restrict__ xb,
                      int n4) {
    int i = blockIdx.x * 256 + threadIdx.x;
    if (i >= n4) return;
    float4 v = ((const float4*)x)[i];
    uint2 r;
    r.x = (uint)f2bf(v.x) | ((uint)f2bf(v.y) << 16);
    r.y = (uint)f2bf(v.z) | ((uint)f2bf(v.w) << 16);
    ((uint2*)xb)[i] = r;
}

// W prep + stat-slot zeroing fused.
__global__ void k_wprep(const float* __restrict__ W1,
                        const float* __restrict__ W2, ushort* __restrict__ Wh,
                        ushort* __restrict__ Wl, float* __restrict__ st,
                        int nSt) {
    int i = blockIdx.x * 256 + threadIdx.x;
    if (i < nSt) st[i] = 0.f;
    if (i >= 6 * 16384) return;
    int l = i >> 14;
    int r = i & 16383;
    int n = r >> 7, k = r & 127;
    const float* W = (l < 3) ? (W1 + l * 16384) : (W2 + (l - 3) * 16384);
    float w = W[k * 128 + n];
    ushort h = f2bf(w);
    Wh[i] = h;
    Wl[i] = f2bf(w - bf2f(h));
}

// ---------------------------------------------------------------------------
// BN+ReLU in-place on bf16 h buffer; coefs from replicated stats slot.
__global__ void k_bnr(ushort* __restrict__ B0,
                      const float* __restrict__ bnstats,
                      const float* __restrict__ gamma,
                      const float* __restrict__ beta, int n4) {
    __shared__ float coef[256];
    int t = threadIdx.x;
    if (t < 128) {
        float s0 = 0.f, q0 = 0.f;
#pragma unroll
        for (int r = 0; r < NREP; ++r) {
            s0 += bnstats[r * 256 + t];
            q0 += bnstats[r * 256 + 128 + t];
        }
        float mu = s0 * INVN;
        float var = q0 * INVN - mu * mu;
        float s = gamma[t] * rsqrtf(var + 1e-5f);
        coef[t] = s;
        coef[128 + t] = beta[t] - mu * s;
    }
    __syncthreads();
    for (int i = blockIdx.x * 256 + t; i < n4; i += gridDim.x * 256) {
        uint4 v = ((const uint4*)B0)[i];
        int c0 = (i & 15) * 8;
        uint u[4] = {v.x, v.y, v.z, v.w};
        uint o[4];
#pragma unroll
        for (int e = 0; e < 4; ++e) {
            float v0 = fmaxf(fmaf(bflo(u[e]), coef[c0 + 2 * e], coef[128 + c0 + 2 * e]), 0.f);
            float v1 = fmaxf(fmaf(bfhi(u[e]), coef[c0 + 2 * e + 1], coef[128 + c0 + 2 * e + 1]), 0.f);
            o[e] = (uint)f2bf(v0) | ((uint)f2bf(v1) << 16);
        }
        ((uint4*)B0)[i] = make_uint4(o[0], o[1], o[2], o[3]);
    }
}

// ---------------------------------------------------------------------------
// CSR build, bucket-radix, no global atomics.  4096-edge chunks; pairs
// packed into 32 bits: (dstLocal<<17)|src.
__global__ void k_bhist(const int* __restrict__ dst, int* __restrict__ cntM,
                        int nE, int nChunks) {
    __shared__ int h[NBKT];
    const int chunk = blockIdx.x, t = threadIdx.x;
    h[t] = 0;
    __syncthreads();
    const int e0 = chunk * ECHUNK;
#pragma unroll
    for (int k = 0; k < 16; ++k) {
        int e = e0 + k * 256 + t;
        if (e < nE) atomicAdd(&h[dst[e] / NPB], 1);
    }
    __syncthreads();
    cntM[t * nChunks + chunk] = h[t];
}

__global__ void k_scanA(int* __restrict__ cnt, int* __restrict__ bsum, int n) {
    __shared__ int s[256];
    int t = threadIdx.x, i = blockIdx.x * 256 + t;
    int v = (i < n) ? cnt[i] : 0;
    s[t] = v;
    __syncthreads();
#pragma unroll
    for (int o = 1; o < 256; o <<= 1) {
        int a = (t >= o) ? s[t - o] : 0;
        __syncthreads();
        s[t] += a;
        __syncthreads();
    }
    if (i < n) cnt[i] = s[t] - v;
    if (t == 255) bsum[blockIdx.x] = s[255];
}

__global__ void k_scanB(int* bsum, int nB) {
    __shared__ int s[1024];
    int t = threadIdx.x;
    int v = (t < nB) ? bsum[t] : 0;
    s[t] = v;
    __syncthreads();
#pragma unroll
    for (int o = 1; o < 1024; o <<= 1) {
        int a = (t >= o) ? s[t - o] : 0;
        __syncthreads();
        s[t] += a;
        __syncthreads();
    }
    if (t < nB) bsum[t] = s[t] - v;
}

__global__ void k_scanC(int* __restrict__ excl, const int* __restrict__ bsum) {
    int i = blockIdx.x * 256 + threadIdx.x;
    excl[i] += bsum[blockIdx.x];
}

__global__ void k_pairs(const int* __restrict__ src, const int* __restrict__ dst,
                        const int* __restrict__ exclM, uint* __restrict__ pairs,
                        int nE, int nChunks) {
    __shared__ int base[NBKT];
    const int chunk = blockIdx.x, t = threadIdx.x;
    base[t] = exclM[t * nChunks + chunk];
    __syncthreads();
    const int e0 = chunk * ECHUNK;
#pragma unroll
    for (int k = 0; k < 16; ++k) {
        int e = e0 + k * 256 + t;
        if (e < nE) {
            int d = dst[e];
            int bkt = d / NPB;
            int pos = atomicAdd(&base[bkt], 1);
            pairs[pos] = ((uint)(d - bkt * NPB) << 17) | (uint)src[e];
        }
    }
}

__global__ void k_csrD(const uint* __restrict__ pairs,
                       const int* __restrict__ exclM, int nChunks,
                       int* __restrict__ rowptr, int* __restrict__ srcs,
                       int nE) {
    __shared__ int cnt[512];
    __shared__ int scn[512];
    __shared__ int sl[BKT_CAP];
    const int b = blockIdx.x, t = threadIdx.x;
    const int base = exclM[b * nChunks];
    const int next = (b == NBKT - 1) ? nE : exclM[(b + 1) * nChunks];
    const int count = next - base;
    const int nodeBase = b * NPB;
    const int nNodes = min(NPB, M_NODES - nodeBase);
    cnt[t] = 0;
    cnt[t + 256] = 0;
    __syncthreads();
    for (int i = t; i < count; i += 256)
        atomicAdd(&cnt[pairs[base + i] >> 17], 1);
    __syncthreads();
    scn[t] = cnt[t];
    scn[t + 256] = cnt[t + 256];
    __syncthreads();
#pragma unroll
    for (int o = 1; o < 512; o <<= 1) {
        int a0 = (t >= o) ? scn[t - o] : 0;
        int a1 = scn[t + 256 - o];
        __syncthreads();
        scn[t] += a0;
        scn[t + 256] += a1;
        __syncthreads();
    }
    int o0 = scn[t] - cnt[t];
    int o1 = scn[t + 256] - cnt[t + 256];
    __syncthreads();
    cnt[t] = o0;
    cnt[t + 256] = o1;
    if (t < nNodes) rowptr[nodeBase + t] = base + o0;
    if (t + 256 < nNodes) rowptr[nodeBase + t + 256] = base + o1;
    if (b == 0 && t == 0) rowptr[M_NODES] = nE;
    __syncthreads();
    const bool inLds = (count <= BKT_CAP);
    for (int i = t; i < count; i += 256) {
        uint p = pairs[base + i];
        int pos = atomicAdd(&cnt[p >> 17], 1);
        int sv = (int)(p & 0x1FFFFu);
        if (inLds) sl[pos] = sv;
        else srcs[base + pos] = sv;
    }
    __syncthreads();
    if (inLds)
        for (int i = t; i < count; i += 256) srcs[base + i] = sl[i];
}

// ---------------------------------------------------------------------------
// Gather: PURE SUM (BN pre-applied by k_bnr).  32 lanes x 4 channels,
// 8 row-loads in flight, two accumulator sets, split planes out.
__global__ void k_gather(const ushort* __restrict__ h,
                         const int* __restrict__ rowptr,
                         const int* __restrict__ srcs,
                         ushort* __restrict__ AGh, ushort* __restrict__ AGl,
                         int M) {
    int t = threadIdx.x;
    int node = blockIdx.x * 8 + (t >> 5);
    if (node >= M) return;
    int c = (t & 31) * 4;
    int beg = rowptr[node];
    int end = rowptr[node + 1];

    uint2 v = *(const uint2*)(h + (size_t)node * DIM + c);
    float a0 = bflo(v.x), a1 = bfhi(v.x), a2 = bflo(v.y), a3 = bfhi(v.y);
    float b0 = 0.f, b1 = 0.f, b2 = 0.f, b3 = 0.f;

    int j = beg;
    for (; j + 8 <= end; j += 8) {
        int s[8];
#pragma unroll
        for (int k = 0; k < 8; ++k) s[k] = srcs[j + k];
        uint2 g[8];
#pragma unroll
        for (int k = 0; k < 8; ++k)
            g[k] = *(const uint2*)(h + (size_t)s[k] * DIM + c);
#pragma unroll
        for (int k = 0; k < 8; k += 2) {
            a0 += bflo(g[k].x); a1 += bfhi(g[k].x);
            a2 += bflo(g[k].y); a3 += bfhi(g[k].y);
            b0 += bflo(g[k + 1].x); b1 += bfhi(g[k + 1].x);
            b2 += bflo(g[k + 1].y); b3 += bfhi(g[k + 1].y);
        }
    }
    for (; j + 4 <= end; j += 4) {
        int s0 = srcs[j], s1 = srcs[j + 1], s2 = srcs[j + 2], s3 = srcs[j + 3];
        uint2 g0 = *(const uint2*)(h + (size_t)s0 * DIM + c);
        uint2 g1 = *(const uint2*)(h + (size_t)s1 * DIM + c);
        uint2 g2 = *(const uint2*)(h + (size_t)s2 * DIM + c);
        uint2 g3 = *(const uint2*)(h + (size_t)s3 * DIM + c);
        a0 += bflo(g0.x); a1 += bfhi(g0.x); a2 += bflo(g0.y); a3 += bfhi(g0.y);
        b0 += bflo(g1.x); b1 += bfhi(g1.x); b2 += bflo(g1.y); b3 += bfhi(g1.y);
        a0 += bflo(g2.x); a1 += bfhi(g2.x); a2 += bflo(g2.y); a3 += bfhi(g2.y);
        b0 += bflo(g3.x); b1 += bfhi(g3.x); b2 += bflo(g3.y); b3 += bfhi(g3.y);
    }
    for (; j < end; ++j) {
        int s = srcs[j];
        uint2 g = *(const uint2*)(h + (size_t)s * DIM + c);
        a0 += bflo(g.x); a1 += bfhi(g.x); a2 += bflo(g.y); a3 += bfhi(g.y);
    }
    float s0 = a0 + b0, s1 = a1 + b1, s2 = a2 + b2, s3 = a3 + b3;
    ushort h0 = f2bf(s0), h1 = f2bf(s1), h2 = f2bf(s2), h3 = f2bf(s3);
    ushort l0 = f2bf(s0 - bf2f(h0)), l1 = f2bf(s1 - bf2f(h1));
    ushort l2 = f2bf(s2 - bf2f(h2)), l3 = f2bf(s3 - bf2f(h3));
    uint2 hp, lp;
    hp.x = (uint)h0 | ((uint)h1 << 16);
    hp.y = (uint)h2 | ((uint)h3 << 16);
    lp.x = (uint)l0 | ((uint)l1 << 16);
    lp.y = (uint)l2 | ((uint)l3 << 16);
    size_t ix = (size_t)node * DIM + c;
    *(uint2*)(AGh + ix) = hp;
    *(uint2*)(AGl + ix) = lp;
}

// ---------------------------------------------------------------------------
// GEMM A: C = (Ah+Al) @ W + bias.  Staging via async global_load_lds
// (width 16): LDS dest LINEAR; swizzle applied by permuting the GLOBAL
// source column (cb ^ (r&15)).  Occupancy 4.
__global__ void __launch_bounds__(256, 4) k_gemmA(
    ushort* __restrict__ Ah, const ushort* __restrict__ Al,
    const ushort* __restrict__ Wh, const ushort* __restrict__ Wl,
    const float* __restrict__ bias, float* __restrict__ statSlot, int M) {
    __shared__ ushort lds[16384];  // 32 KB
    const int t = threadIdx.x;
    const int w = t >> 6, lane = t & 63, rq = lane >> 4, rc = lane & 15;
    const int row0 = blockIdx.x * 64;

    bf16x8 wh[4][2], wl[4][2];
#pragma unroll
    for (int kc = 0; kc < 4; ++kc)
#pragma unroll
        for (int jj = 0; jj < 2; ++jj) {
            size_t off = (size_t)(w * 32 + jj * 16 + rc) * DIM + kc * 32 + rq * 8;
            wh[kc][jj] = *(const bf16x8*)(Wh + off);
            wl[kc][jj] = *(const bf16x8*)(Wl + off);
        }

#pragma unroll
    for (int i = 0; i < 8; ++i) {
        int idx = t + i * 256;
        int pl = idx >> 10;
        int r = (idx >> 4) & 63;
        int cb = idx & 15;
        int cbs = cb ^ (r & 15);  // pre-swizzled source column
        const ushort* p = pl ? Al : Ah;
        const ushort* g = p + (size_t)(row0 + r) * DIM + cbs * 8;
        __builtin_amdgcn_global_load_lds(
            (const __attribute__((address_space(1))) void*)g,
            (__attribute__((address_space(3))) void*)((char*)lds + idx * 16),
            16, 0, 0);
    }
    __syncthreads();

    f32x4 acc[4][2];
#pragma unroll
    for (int i = 0; i < 4; ++i)
#pragma unroll
        for (int jj = 0; jj < 2; ++jj) acc[i][jj] = (f32x4){0.f, 0.f, 0.f, 0.f};

#pragma unroll
    for (int kc = 0; kc < 4; ++kc) {
        const int kb = kc * 64 + rq * 16;
#pragma unroll
        for (int i = 0; i < 4; ++i) {
            int lr = i * 16 + rc;
            int so = lr * 256 + (kb ^ ((lr & 15) << 4));
            bf16x8 ah = *(const bf16x8*)((char*)lds + so);
            bf16x8 al = *(const bf16x8*)((char*)lds + 16384 + so);
#pragma unroll
            for (int jj = 0; jj < 2; ++jj) {
                acc[i][jj] = __builtin_amdgcn_mfma_f32_16x16x32_bf16(ah, wh[kc][jj], acc[i][jj], 0, 0, 0);
                acc[i][jj] = __builtin_amdgcn_mfma_f32_16x16x32_bf16(al, wh[kc][jj], acc[i][jj], 0, 0, 0);
                acc[i][jj] = __builtin_amdgcn_mfma_f32_16x16x32_bf16(ah, wl[kc][jj], acc[i][jj], 0, 0, 0);
            }
        }
    }

    float bc[2] = {bias[w * 32 + rc], bias[w * 32 + 16 + rc]};
    float csum[2] = {0.f, 0.f}, csq[2] = {0.f, 0.f};

    __syncthreads();
#pragma unroll
    for (int i = 0; i < 4; ++i)
#pragma unroll
        for (int r = 0; r < 4; ++r) {
            int lrow = i * 16 + rq * 4 + r;
            bool live = (row0 + lrow) < M;
#pragma unroll
            for (int jj = 0; jj < 2; ++jj) {
                float o = acc[i][jj][r] + bc[jj];
                int off = lrow * 256 +
                          (((w * 32 + jj * 16 + rc) * 2) ^ ((lrow & 15) << 4));
                *(ushort*)((char*)lds + off) = f2bf(o);
                if (live) { csum[jj] += o; csq[jj] += o * o; }
            }
        }
    __syncthreads();
    {
        int lrow = w * 16 + (lane & 15);
        int kq = lane >> 4;
        ushort* dH = Ah + (size_t)row0 * DIM;
#pragma unroll
        for (int kc = 0; kc < 4; ++kc) {
            int off = lrow * 256 + ((kc * 64 + kq * 16) ^ ((lrow & 15) << 4));
            uint4 H = *(uint4*)((char*)lds + off);
            size_t go = ((size_t)(w * 4 + kc) * 64 + lane) * 8;
            *(uint4*)(dH + go) = H;
        }
    }
#pragma unroll
    for (int jj = 0; jj < 2; ++jj) {
        csum[jj] += __shfl_xor(csum[jj], 16);
        csum[jj] += __shfl_xor(csum[jj], 32);
        csq[jj] += __shfl_xor(csq[jj], 16);
        csq[jj] += __shfl_xor(csq[jj], 32);
    }
    float* slot = statSlot + (blockIdx.x & (NREP - 1)) * 256;
    if (lane < 16) {
        atomicAdd(slot + w * 32 + rc, csum[0]);
        atomicAdd(slot + w * 32 + 16 + rc, csum[1]);
        atomicAdd(slot + 128 + w * 32 + rc, csq[0]);
        atomicAdd(slot + 128 + w * 32 + 16 + rc, csq[1]);
    }
}

// ---------------------------------------------------------------------------
// GEMM B: C = BNrelu(Ch) @ W + bias.  A read from fragment-layout plane;
// BN+split in registers.  bf16 Cb + stats, or fused L2-normalize to f32.
__global__ void __launch_bounds__(256, 4) k_gemmB(
    const ushort* __restrict__ Ch,
    const ushort* __restrict__ Wh, const ushort* __restrict__ Wl,
    const float* __restrict__ bias, const float* __restrict__ bnstats,
    const float* __restrict__ gamma, const float* __restrict__ beta,
    ushort* __restrict__ Cb, float* __restrict__ outF,
    float* __restrict__ statSlot, int M) {
    __shared__ char smem[16384];
    const int t = threadIdx.x;
    const int w = t >> 6, lane = t & 63, rq = lane >> 4, rc = lane & 15;
    const int row0 = blockIdx.x * 64;

    bf16x8 wh[4][2], wl[4][2];
#pragma unroll
    for (int kc = 0; kc < 4; ++kc)
#pragma unroll
        for (int jj = 0; jj < 2; ++jj) {
            size_t off = (size_t)(w * 32 + jj * 16 + rc) * DIM + kc * 32 + rq * 8;
            wh[kc][jj] = *(const bf16x8*)(Wh + off);
            wl[kc][jj] = *(const bf16x8*)(Wl + off);
        }

    float* coef = (float*)smem;
    if (t < 128) {
        float s0 = 0.f, q0 = 0.f;
#pragma unroll
        for (int r = 0; r < NREP; ++r) {
            s0 += bnstats[r * 256 + t];
            q0 += bnstats[r * 256 + 128 + t];
        }
        float mu = s0 * INVN;
        float var = q0 * INVN - mu * mu;
        float s = gamma[t] * rsqrtf(var + 1e-5f);
        coef[t] = s;
        coef[128 + t] = beta[t] - mu * s;
    }
    __syncthreads();

    const ushort* pH = Ch + (size_t)row0 * DIM;
    const int kq8 = (lane >> 4) * 8;

    f32x4 acc[4][2];
#pragma unroll
    for (int i = 0; i < 4; ++i)
#pragma unroll
        for (int jj = 0; jj < 2; ++jj) acc[i][jj] = (f32x4){0.f, 0.f, 0.f, 0.f};

#pragma unroll
    for (int kc = 0; kc < 4; ++kc) {
        float sc8[8], sh8[8];
#pragma unroll
        for (int e = 0; e < 8; ++e) {
            sc8[e] = coef[kc * 32 + kq8 + e];
            sh8[e] = coef[128 + kc * 32 + kq8 + e];
        }
#pragma unroll
        for (int i = 0; i < 4; ++i) {
            size_t go = ((size_t)(i * 4 + kc) * 64 + lane) * 8;
            uint4 H = *(const uint4*)(pH + go);
            uint hu[4] = {H.x, H.y, H.z, H.w};
            uint oh[4], ol[4];
#pragma unroll
            for (int e = 0; e < 4; ++e) {
                float v0 = bflo(hu[e]);
                float v1 = bfhi(hu[e]);
                v0 = fmaxf(fmaf(v0, sc8[2 * e], sh8[2 * e]), 0.f);
                v1 = fmaxf(fmaf(v1, sc8[2 * e + 1], sh8[2 * e + 1]), 0.f);
                ushort h0 = f2bf(v0), h1 = f2bf(v1);
                oh[e] = (uint)h0 | ((uint)h1 << 16);
                ol[e] = (uint)f2bf(v0 - bf2f(h0)) |
                        ((uint)f2bf(v1 - bf2f(h1)) << 16);
            }
            uint4 AH = make_uint4(oh[0], oh[1], oh[2], oh[3]);
            uint4 AL = make_uint4(ol[0], ol[1], ol[2], ol[3]);
            bf16x8 ah = *(bf16x8*)&AH;
            bf16x8 al = *(bf16x8*)&AL;
#pragma unroll
            for (int jj = 0; jj < 2; ++jj) {
                acc[i][jj] = __builtin_amdgcn_mfma_f32_16x16x32_bf16(ah, wh[kc][jj], acc[i][jj], 0, 0, 0);
                acc[i][jj] = __builtin_amdgcn_mfma_f32_16x16x32_bf16(al, wh[kc][jj], acc[i][jj], 0, 0, 0);
                acc[i][jj] = __builtin_amdgcn_mfma_f32_16x16x32_bf16(ah, wl[kc][jj], acc[i][jj], 0, 0, 0);
            }
        }
    }

    float bc[2] = {bias[w * 32 + rc], bias[w * 32 + 16 + rc]};

    if (outF) {
#pragma unroll
        for (int i = 0; i < 4; ++i)
#pragma unroll
            for (int r = 0; r < 4; ++r)
#pragma unroll
                for (int jj = 0; jj < 2; ++jj) acc[i][jj][r] += bc[jj];
        __syncthreads();
        float* nr = (float*)smem;
#pragma unroll
        for (int i = 0; i < 4; ++i)
#pragma unroll
            for (int r = 0; r < 4; ++r) {
                float ss = acc[i][0][r] * acc[i][0][r] + acc[i][1][r] * acc[i][1][r];
                ss += __shfl_xor(ss, 1);
                ss += __shfl_xor(ss, 2);
                ss += __shfl_xor(ss, 4);
                ss += __shfl_xor(ss, 8);
                if (rc == 0) nr[(i * 16 + rq * 4 + r) * 4 + w] = ss;
            }
        __syncthreads();
#pragma unroll
        for (int i = 0; i < 4; ++i)
#pragma unroll
            for (int r = 0; r < 4; ++r) {
                int lrow = i * 16 + rq * 4 + r;
                float4 q = *(const float4*)(nr + lrow * 4);
                float inv = 1.f / fmaxf(sqrtf(q.x + q.y + q.z + q.w), 1e-12f);
                int row = row0 + lrow;
                if (row < M) {
                    outF[(size_t)row * DIM + w * 32 + rc] = acc[i][0][r] * inv;
                    outF[(size_t)row * DIM + w * 32 + 16 + rc] = acc[i][1][r] * inv;
                }
            }
        return;
    }

    float csum[2] = {0.f, 0.f}, csq[2] = {0.f, 0.f};
    __syncthreads();
#pragma unroll
    for (int i = 0; i < 4; ++i)
#pragma unroll
        for (int r = 0; r < 4; ++r) {
            int lrow = i * 16 + rq * 4 + r;
            bool live = (row0 + lrow) < M;
#pragma unroll
            for (int jj = 0; jj < 2; ++jj) {
                float o = acc[i][jj][r] + bc[jj];
                int off = lrow * 256 +
                          (((w * 32 + jj * 16 + rc) * 2) ^ ((lrow & 15) << 4));
                *(ushort*)(smem + off) = f2bf(o);
                if (live) { csum[jj] += o; csq[jj] += o * o; }
            }
        }
    __syncthreads();
#pragma unroll
    for (int it = 0; it < 4; ++it) {
        int idx = t + it * 256;
        int row = idx >> 4, cb = idx & 15;
        int grow = row0 + row;
        if (grow < M) {
            uint4 v = *(uint4*)(smem + row * 256 + ((cb * 16) ^ ((row & 15) << 4)));
            *(uint4*)(Cb + (size_t)grow * DIM + cb * 8) = v;
        }
    }
#pragma unroll
    for (int jj = 0; jj < 2; ++jj) {
        csum[jj] += __shfl_xor(csum[jj], 16);
        csum[jj] += __shfl_xor(csum[jj], 32);
        csq[jj] += __shfl_xor(csq[jj], 16);
        csq[jj] += __shfl_xor(csq[jj], 32);
    }
    float* slot = statSlot + (blockIdx.x & (NREP - 1)) * 256;
    if (lane < 16) {
        atomicAdd(slot + w * 32 + rc, csum[0]);
        atomicAdd(slot + w * 32 + 16 + rc, csum[1]);
        atomicAdd(slot + 128 + w * 32 + rc, csq[0]);
        atomicAdd(slot + 128 + w * 32 + 16 + rc, csq[1]);
    }
}

// ---------------------------------------------------------------------------
extern "C" void kernel_launch(void* const* d_in, const int* in_sizes, int n_in,
                              void* d_out, int out_size, void* d_ws,
                              size_t ws_size, hipStream_t stream) {
    const float* x = (const float*)d_in[0];
    const int* ei = (const int*)d_in[1];
    const float* W1 = (const float*)d_in[2];
    const float* b1 = (const float*)d_in[3];
    const float* g1 = (const float*)d_in[4];
    const float* be1 = (const float*)d_in[5];
    const float* W2 = (const float*)d_in[6];
    const float* b2 = (const float*)d_in[7];
    const float* g_out = (const float*)d_in[8];
    const float* b_out = (const float*)d_in[9];
    float* out = (float*)d_out;

    const int M = M_NODES;
    const int E = N_EDGES_TOT;
    const size_t NM = (size_t)M * DIM;
    const size_t PM = (size_t)PADM * DIM;
    const int nChunks = (E + ECHUNK - 1) / ECHUNK;   // 391
    const int nMat = NBKT * nChunks;                 // 100096
    const int SLOT = 256 * NREP;

    ushort* AGh = (ushort*)d_ws;
    ushort* AGl = AGh + PM;
    ushort* B0 = AGl + PM;
    ushort* Wh = B0 + NM;
    ushort* Wl = Wh + 6 * 16384;
    float* st = (float*)(Wl + 6 * 16384);
    float* stA0 = st;
    float* stA1 = st + SLOT;
    float* stA2 = st + 2 * SLOT;
    float* stB0 = st + 3 * SLOT;
    float* stB1 = st + 4 * SLOT;
    uint* pairs = (uint*)(st + 5 * SLOT);
    int* rowptr = (int*)(pairs + E);
    int* cntM = rowptr + (M + 2);
    int* bsum = cntM + nMat;
    int* srcs = bsum + 1024;

    const int* src = ei;
    const int* dst = ei + E;

    const int gemmGrid = PADM / 64;    // 1563
    const int gathGrid = (M + 7) / 8;
    const int n4 = (int)(NM / 8);

    // ---------------- CSR build ----------------
    k_bhist<<<nChunks, 256, 0, stream>>>(dst, cntM, E, nChunks);
    k_scanA<<<(nMat + 255) / 256, 256, 0, stream>>>(cntM, bsum, nMat);
    k_scanB<<<1, 1024, 0, stream>>>(bsum, (nMat + 255) / 256);
    k_scanC<<<(nMat + 255) / 256, 256, 0, stream>>>(cntM, bsum);
    k_pairs<<<nChunks, 256, 0, stream>>>(src, dst, cntM, pairs, E, nChunks);
    k_csrD<<<NBKT, 256, 0, stream>>>(pairs, cntM, nChunks, rowptr, srcs, E);

    // ---------------- prep ----------------
    k_cvt<<<(int)((NM / 4 + 255) / 256), 256, 0, stream>>>(x, B0, (int)(NM / 4));
    k_wprep<<<(6 * 16384 + 255) / 256, 256, 0, stream>>>(W1, W2, Wh, Wl, st, 5 * SLOT);

    // ---------------- layer 0 ----------------
    k_gather<<<gathGrid, 256, 0, stream>>>(B0, rowptr, srcs, AGh, AGl, M);
    k_gemmA<<<gemmGrid, 256, 0, stream>>>(AGh, AGl, Wh, Wl, b1, stA0, M);
    k_gemmB<<<gemmGrid, 256, 0, stream>>>(AGh, Wh + 3 * 16384, Wl + 3 * 16384,
                                          b2, stA0, g1, be1, B0, nullptr, stB0, M);
    k_bnr<<<2048, 256, 0, stream>>>(B0, stB0, g_out, b_out, n4);

    // ---------------- layer 1 ----------------
    k_gather<<<gathGrid, 256, 0, stream>>>(B0, rowptr, srcs, AGh, AGl, M);
    k_gemmA<<<gemmGrid, 256, 0, stream>>>(AGh, AGl, Wh + 16384, Wl + 16384,
                                          b1 + 128, stA1, M);
    k_gemmB<<<gemmGrid, 256, 0, stream>>>(AGh, Wh + 4 * 16384, Wl + 4 * 16384,
                                          b2 + 128, stA1, g1 + 128, be1 + 128,
                                          B0, nullptr, stB1, M);
    k_bnr<<<2048, 256, 0, stream>>>(B0, stB1, g_out + 128, b_out + 128, n4);

    // ---------------- layer 2 ----------------
    k_gather<<<gathGrid, 256, 0, stream>>>(B0, rowptr, srcs, AGh, AGl, M);
    k_gemmA<<<gemmGrid, 256, 0, stream>>>(AGh, AGl, Wh + 2 * 16384, Wl + 2 * 16384,
                                          b1 + 256, stA2, M);
    k_gemmB<<<gemmGrid, 256, 0, stream>>>(AGh, Wh + 5 * 16384, Wl + 5 * 16384,
                                          b2 + 256, stA2, g1 + 256, be1 + 256,
                                          nullptr, out, nullptr, M);
}